// Round 3
// baseline (11453.460 us; speedup 1.0000x reference)
//
#include <hip/hip_runtime.h>
#include <math.h>

// Problem constants
#define BATCH 128
#define TENC  64
#define EE    256
#define DD    256
#define NSTEP 63

// Workspace layout (FLOAT offsets)
#define OFF_WA1ET  0         // [256 k][256 j] f32 : W_a1[j][512+k]   (enc part, for enc_proj)
#define OFF_EPT    65536     // [128 b][256 j][64 t] f32 : b_a1[j] + enc[b][t]·W_a1[j,512:]
#define OFF_PKH    2162688   // fp16 region (half offsets within):
                             //   PK1: [0,131072)   = [p<4][kk<16][j<256][m<8] = Wa1[j][p*128+kk*8+m]
                             //   PK4: [131072, 393216) = [kk<32][q<1024][m<8] = Whh[q][kk*8+m]
// total floats = 2162688 + 196608 = 2359296 (~9.0 MB)

typedef __attribute__((ext_vector_type(8))) _Float16 half8;

__device__ __forceinline__ float ftanh(float x) {
    x = fminf(15.f, fmaxf(-15.f, x));
    float e = __expf(2.f * x);
    return (e - 1.f) / (e + 1.f);
}
__device__ __forceinline__ float fsig(float x) {
    return 1.f / (1.f + __expf(-x));
}

// ---------------------------------------------------------------------------
// Pre-kernel A: pack weights (fp16 stream-ordered) + WA1ET (f32)
// ---------------------------------------------------------------------------
__global__ void pack_weights(const float* __restrict__ Wa1,
                             const float* __restrict__ Whh,
                             float* __restrict__ ws) {
    int idx = blockIdx.x * blockDim.x + threadIdx.x;
    _Float16* PKH = (_Float16*)(ws + OFF_PKH);
    if (idx < 131072) {
        // PK1 flat = p*32768 + kk*2048 + j*8 + m  ->  Wa1[j][p*128 + kk*8 + m]
        int m = idx & 7, j = (idx >> 3) & 255, kk = (idx >> 11) & 15, p = idx >> 15;
        int k = p * 128 + kk * 8 + m;
        PKH[idx] = (_Float16)Wa1[j * 768 + k];
    } else if (idx < 393216) {
        // PK4 flat = kk*8192 + q*8 + m  ->  Whh[q][kk*8 + m]
        int n = idx - 131072;
        int m = n & 7, q = (n >> 3) & 1023, kk = n >> 13;
        PKH[131072 + n] = (_Float16)Whh[q * 256 + kk * 8 + m];
    } else if (idx < 458752) {
        // WA1ET[k][j] = Wa1[j][512+k]  (f32)
        int n = idx - 393216;
        int k = n >> 8, j = n & 255;
        ws[OFF_WA1ET + n] = Wa1[j * 768 + 512 + k];
    }
}

// ---------------------------------------------------------------------------
// Pre-kernel B: EPT[b][j][t] = b_a1[j] + sum_k enc[b][t][k] * W_a1[j][512+k]
// ---------------------------------------------------------------------------
__global__ void enc_proj_kernel(const float* __restrict__ enc,
                                const float* __restrict__ ba1,
                                float* __restrict__ ws) {
    __shared__ float smem[8448];
    const int b  = blockIdx.x >> 1;
    const int th = blockIdx.x & 1;
    const int t0 = th * 32;
    const int tid = threadIdx.x;

    const float* encb = enc + (b * TENC + t0) * 256;
    for (int c = 0; c < 32; ++c) smem[c * 256 + tid] = encb[c * 256 + tid];
    __syncthreads();

    const int w = tid >> 6, l = tid & 63;
    float acc[8][4];
    #pragma unroll
    for (int a = 0; a < 8; ++a)
        #pragma unroll
        for (int c = 0; c < 4; ++c) acc[a][c] = 0.f;

    const float4* WT = (const float4*)(ws + OFF_WA1ET);
    for (int k = 0; k < 256; ++k) {
        float4 wv = WT[k * 64 + l];
        #pragma unroll
        for (int tt = 0; tt < 8; ++tt) {
            float e = smem[(w * 8 + tt) * 256 + k];
            acc[tt][0] += e * wv.x; acc[tt][1] += e * wv.y;
            acc[tt][2] += e * wv.z; acc[tt][3] += e * wv.w;
        }
    }
    float4 bb = ((const float4*)ba1)[l];
    __syncthreads();
    #pragma unroll
    for (int tt = 0; tt < 8; ++tt) {
        smem[(4 * l + 0) * 33 + w * 8 + tt] = acc[tt][0] + bb.x;
        smem[(4 * l + 1) * 33 + w * 8 + tt] = acc[tt][1] + bb.y;
        smem[(4 * l + 2) * 33 + w * 8 + tt] = acc[tt][2] + bb.z;
        smem[(4 * l + 3) * 33 + w * 8 + tt] = acc[tt][3] + bb.w;
    }
    __syncthreads();
    float* EPT = ws + OFF_EPT + b * 16384;
    for (int c = 0; c < 32; ++c) {
        int i = c * 256 + tid;
        int j = i >> 5, t5 = i & 31;
        EPT[j * 64 + t0 + t5] = smem[j * 33 + t5];
    }
}

// ---------------------------------------------------------------------------
// Main kernel: one workgroup per batch element, 1024 threads, 63 scan steps.
// Weight streams are fp16, packed so each wave load = 1 KiB contiguous.
// ---------------------------------------------------------------------------
__global__ __launch_bounds__(1024) void decoder_main(
    const float* __restrict__ enc, const float* __restrict__ yhist,
    const float* __restrict__ Wa2,
    const float* __restrict__ Wfc, const float* __restrict__ bfc,
    const float* __restrict__ wih, const float* __restrict__ bih,
    const float* __restrict__ bhh,
    const float* __restrict__ Wff, const float* __restrict__ bff,
    const float* __restrict__ ws, float* __restrict__ out) {

    __shared__ float hc[512];        // h = [0,256), c = [256,512)
    __shared__ float red1[1024];     // P1 partials [4 k-chunks][256 j]
    __shared__ float red2[1024];     // P2 partials [16 j-chunks][64 t]
    __shared__ float red3[1024];     // P3 partials [4 t-chunks][256 e]
    __shared__ float gbuf[1024];
    __shared__ float attnw[64];
    __shared__ float wa2s[256];
    __shared__ float wfcs[257];
    __shared__ float ys[64];
    __shared__ float ytil_s;
    __shared__ float epl[16384];     // EPT[b] : [256 j][64 t]
    __shared__ float encl[16384];    // enc[b] : [64 t][256 e]

    const int b    = blockIdx.x;
    const int tid  = threadIdx.x;
    const int lane = tid & 63;
    const int wv   = tid >> 6;

    // ---- stage per-batch data into LDS once ----
    const float* EPTb = ws + OFF_EPT + b * 16384;
    const float* encb = enc + b * 16384;
    #pragma unroll
    for (int i = 0; i < 16; ++i) {
        epl[i * 1024 + tid]  = EPTb[i * 1024 + tid];
        encl[i * 1024 + tid] = encb[i * 1024 + tid];
    }
    if (tid < 512) hc[tid] = 0.f;
    if (tid < 256) wa2s[tid] = Wa2[tid];
    if (tid < 257) wfcs[tid] = Wfc[tid];
    if (tid < NSTEP) ys[tid] = yhist[b * NSTEP + tid];
    const float bfc0 = bfc[0];
    const float wi   = wih[tid];                 // 4D x 1 -> per-thread gate row
    const float bsum = bih[tid] + bhh[tid];
    __syncthreads();

    const _Float16* PKH = (const _Float16*)(ws + OFF_PKH);
    const half8* PK1 = (const half8*)PKH;                  // [p][kk][j] half8
    const half8* PK4 = (const half8*)(PKH + 131072);       // [kk][q]    half8

    for (int step = 0; step < NSTEP; ++step) {
        // ---- P1 partials: red1[p][j] = sum_{k in chunk p} hc[k]*Wa1[j][k] ----
        {
            const int p = tid >> 8, j = tid & 255;
            const half8* W1 = PK1 + (p * 16) * 256 + j;
            const float* hp = hc + p * 128;
            float a0 = 0.f, a1 = 0.f;
            #pragma unroll
            for (int kk = 0; kk < 16; ++kk) {
                half8 w = W1[kk * 256];
                #pragma unroll
                for (int m = 0; m < 8; m += 2) {
                    a0 += hp[kk * 8 + m]     * (float)w[m];
                    a1 += hp[kk * 8 + m + 1] * (float)w[m + 1];
                }
            }
            red1[p * 256 + j] = a0 + a1;
        }
        // ---- P4 accumulate (registers): g[q] = h @ W_hh[q,:] ----
        float g0 = 0.f, g1 = 0.f;
        {
            const half8* W4 = PK4 + tid;                   // q = tid
            #pragma unroll
            for (int kk = 0; kk < 32; ++kk) {
                half8 w = W4[kk * 1024];
                #pragma unroll
                for (int m = 0; m < 8; m += 2) {
                    g0 += hc[kk * 8 + m]     * (float)w[m];
                    g1 += hc[kk * 8 + m + 1] * (float)w[m + 1];
                }
            }
        }
        __syncthreads();                                 // S1: red1 ready

        // ---- P2: scores s[t] = sum_j tanh(ep[j][t] + z[j]) * wa2[j] ----
        {
            float partial = 0.f;
            const int jbase = wv * 16;
            #pragma unroll
            for (int jj = 0; jj < 16; ++jj) {
                const int j = jbase + jj;
                float zj = red1[j] + red1[256 + j] + red1[512 + j] + red1[768 + j];
                float v = epl[j * 64 + lane] + zj;
                partial += ftanh(v) * wa2s[j];
            }
            red2[wv * 64 + lane] = partial;
        }
        __syncthreads();                                 // S2: red2 ready
        if (wv == 0) {
            float s = 0.f;
            #pragma unroll
            for (int w2 = 0; w2 < 16; ++w2) s += red2[w2 * 64 + lane];
            float m = s;
            #pragma unroll
            for (int d = 32; d >= 1; d >>= 1) m = fmaxf(m, __shfl_xor(m, d));
            float e = __expf(s - m);
            float su = e;
            #pragma unroll
            for (int d = 32; d >= 1; d >>= 1) su += __shfl_xor(su, d);
            attnw[lane] = e / su;
        }
        __syncthreads();                                 // S3: attnw ready

        // ---- P3: ctx partials ctx[e] = sum_t attn[t] * enc[t][e] ----
        {
            const int e = tid & 255, tc = tid >> 8;
            float partial = 0.f;
            #pragma unroll
            for (int i = 0; i < 16; ++i) {
                const int t = tc * 16 + i;
                partial += attnw[t] * encl[t * 256 + e];
            }
            red3[tc * 256 + e] = partial;
        }
        __syncthreads();                                 // S4: red3 ready
        if (wv == 0) {
            float partial = 0.f;
            #pragma unroll
            for (int q = 0; q < 4; ++q) {
                const int e2 = q * 64 + lane;
                float cv = red3[e2] + red3[256 + e2] + red3[512 + e2] + red3[768 + e2];
                partial += cv * wfcs[e2];
            }
            #pragma unroll
            for (int d = 32; d >= 1; d >>= 1) partial += __shfl_xor(partial, d);
            if (lane == 0) ytil_s = partial + wfcs[256] * ys[step] + bfc0;
        }
        __syncthreads();                                 // S5: ytil ready

        // ---- gates finalize + write ----
        gbuf[tid] = g0 + g1 + ytil_s * wi + bsum;
        __syncthreads();                                 // S6: gates ready

        // ---- h, c update (PyTorch gate order i,f,g,o) ----
        if (tid < 256) {
            float gi = gbuf[tid], gf = gbuf[256 + tid];
            float gg = gbuf[512 + tid], go = gbuf[768 + tid];
            float cn = fsig(gf) * hc[256 + tid] + fsig(gi) * ftanh(gg);
            float hn = fsig(go) * ftanh(cn);
            hc[tid] = hn; hc[256 + tid] = cn;
        }
        __syncthreads();                                 // S7: hc ready
    }

    // ---- epilogue: out[b][r] = b_ff[r] + [h, ctx] . W_ff[r]  (ctx from red3) ----
    if (wv < 2) {
        float partial = 0.f;
        #pragma unroll
        for (int qq = 0; qq < 8; ++qq) {
            const int e2 = qq * 64 + lane;
            float v;
            if (e2 < 256) {
                v = hc[e2];
            } else {
                const int e = e2 - 256;
                v = red3[e] + red3[256 + e] + red3[512 + e] + red3[768 + e];
            }
            partial += v * Wff[wv * 512 + e2];
        }
        #pragma unroll
        for (int d = 32; d >= 1; d >>= 1) partial += __shfl_xor(partial, d);
        if (lane == 0) out[b * 2 + wv] = partial + bff[wv];
    }
}

// ---------------------------------------------------------------------------
extern "C" void kernel_launch(void* const* d_in, const int* in_sizes, int n_in,
                              void* d_out, int out_size, void* d_ws, size_t ws_size,
                              hipStream_t stream) {
    const float* enc = (const float*)d_in[0];
    const float* yh  = (const float*)d_in[1];
    const float* Wa1 = (const float*)d_in[2];
    const float* ba1 = (const float*)d_in[3];
    const float* Wa2 = (const float*)d_in[4];
    // d_in[5] = b_a2 : softmax shift-invariant, unused
    const float* Wfc = (const float*)d_in[6];
    const float* bfc = (const float*)d_in[7];
    const float* Wih = (const float*)d_in[8];
    const float* Whh = (const float*)d_in[9];
    const float* bih = (const float*)d_in[10];
    const float* bhh = (const float*)d_in[11];
    const float* Wff = (const float*)d_in[12];
    const float* bff = (const float*)d_in[13];
    float* ws  = (float*)d_ws;
    float* out = (float*)d_out;

    hipLaunchKernelGGL(pack_weights, dim3(1792), dim3(256), 0, stream, Wa1, Whh, ws);
    hipLaunchKernelGGL(enc_proj_kernel, dim3(256), dim3(256), 0, stream, enc, ba1, ws);
    hipLaunchKernelGGL(decoder_main, dim3(BATCH), dim3(1024), 0, stream,
                       enc, yh, Wa2, Wfc, bfc, Wih, bih, bhh, Wff, bff, ws, out);
}

// Round 4
// 714.622 us; speedup vs baseline: 16.0273x; 16.0273x over previous
//
#include <hip/hip_runtime.h>
#include <math.h>

// Problem constants
#define BATCH 128
#define TENC  64
#define EE    256
#define DD    256
#define NSTEP 63

// Workspace layout (FLOAT offsets)
#define OFF_WA1ET  0         // [256 k][256 j] f32 : W_a1[j][512+k]   (enc part, for enc_proj)
#define OFF_EPT    65536     // [128 b][256 j][64 t] f32 : b_a1[j] + enc[b][t]·W_a1[j,512:]
#define OFF_PKH    2162688   // fp16 region (half offsets within):
                             //   PK1: [0,131072)   = [p<4][kk<16][j<256][m<8] = Wa1[j][p*128+kk*8+m]
                             //   PK4: [131072, 393216) = [kk<32][q<1024][m<8] = Whh[q][kk*8+m]

typedef __attribute__((ext_vector_type(8))) _Float16 half8;

__device__ __forceinline__ float ftanh(float x) {
    x = fminf(15.f, fmaxf(-15.f, x));
    float e = __expf(2.f * x);
    return (e - 1.f) / (e + 1.f);
}
__device__ __forceinline__ float fsig(float x) {
    return 1.f / (1.f + __expf(-x));
}

// ---------------------------------------------------------------------------
// Pre-kernel A: pack weights (fp16 stream-ordered) + WA1ET (f32)
// ---------------------------------------------------------------------------
__global__ void pack_weights(const float* __restrict__ Wa1,
                             const float* __restrict__ Whh,
                             float* __restrict__ ws) {
    int idx = blockIdx.x * blockDim.x + threadIdx.x;
    _Float16* PKH = (_Float16*)(ws + OFF_PKH);
    if (idx < 131072) {
        // PK1 flat = p*32768 + kk*2048 + j*8 + m  ->  Wa1[j][p*128 + kk*8 + m]
        int m = idx & 7, j = (idx >> 3) & 255, kk = (idx >> 11) & 15, p = idx >> 15;
        int k = p * 128 + kk * 8 + m;
        PKH[idx] = (_Float16)Wa1[j * 768 + k];
    } else if (idx < 393216) {
        // PK4 flat = kk*8192 + q*8 + m  ->  Whh[q][kk*8 + m]
        int n = idx - 131072;
        int m = n & 7, q = (n >> 3) & 1023, kk = n >> 13;
        PKH[131072 + n] = (_Float16)Whh[q * 256 + kk * 8 + m];
    } else if (idx < 458752) {
        // WA1ET[k][j] = Wa1[j][512+k]  (f32)
        int n = idx - 393216;
        int k = n >> 8, j = n & 255;
        ws[OFF_WA1ET + n] = Wa1[j * 768 + 512 + k];
    }
}

// ---------------------------------------------------------------------------
// Pre-kernel B: EPT[b][j][t] = b_a1[j] + sum_k enc[b][t][k] * W_a1[j][512+k]
// ---------------------------------------------------------------------------
__global__ void enc_proj_kernel(const float* __restrict__ enc,
                                const float* __restrict__ ba1,
                                float* __restrict__ ws) {
    __shared__ float smem[8448];
    const int b  = blockIdx.x >> 1;
    const int th = blockIdx.x & 1;
    const int t0 = th * 32;
    const int tid = threadIdx.x;

    const float* encb = enc + (b * TENC + t0) * 256;
    for (int c = 0; c < 32; ++c) smem[c * 256 + tid] = encb[c * 256 + tid];
    __syncthreads();

    const int w = tid >> 6, l = tid & 63;
    float acc[8][4];
    #pragma unroll
    for (int a = 0; a < 8; ++a)
        #pragma unroll
        for (int c = 0; c < 4; ++c) acc[a][c] = 0.f;

    const float4* WT = (const float4*)(ws + OFF_WA1ET);
    for (int k = 0; k < 256; ++k) {
        float4 wv = WT[k * 64 + l];
        #pragma unroll
        for (int tt = 0; tt < 8; ++tt) {
            float e = smem[(w * 8 + tt) * 256 + k];
            acc[tt][0] += e * wv.x; acc[tt][1] += e * wv.y;
            acc[tt][2] += e * wv.z; acc[tt][3] += e * wv.w;
        }
    }
    float4 bb = ((const float4*)ba1)[l];
    __syncthreads();
    #pragma unroll
    for (int tt = 0; tt < 8; ++tt) {
        smem[(4 * l + 0) * 33 + w * 8 + tt] = acc[tt][0] + bb.x;
        smem[(4 * l + 1) * 33 + w * 8 + tt] = acc[tt][1] + bb.y;
        smem[(4 * l + 2) * 33 + w * 8 + tt] = acc[tt][2] + bb.z;
        smem[(4 * l + 3) * 33 + w * 8 + tt] = acc[tt][3] + bb.w;
    }
    __syncthreads();
    float* EPT = ws + OFF_EPT + b * 16384;
    for (int c = 0; c < 32; ++c) {
        int i = c * 256 + tid;
        int j = i >> 5, t5 = i & 31;
        EPT[j * 64 + t0 + t5] = smem[j * 33 + t5];
    }
}

// ---------------------------------------------------------------------------
// Main kernel: one workgroup per batch element, 1024 threads, 63 scan steps.
// Weight streams fp16, packed so each wave load = 1 KiB contiguous.
// __launch_bounds__(1024, 4): 4 waves/EU = 1 WG/CU -> 128-VGPR cap (no spills);
// 128 WGs on 256 CUs can't use more than 1 WG/CU anyway.
// ---------------------------------------------------------------------------
__global__ __launch_bounds__(1024, 4) void decoder_main(
    const float* __restrict__ enc, const float* __restrict__ yhist,
    const float* __restrict__ Wa2,
    const float* __restrict__ Wfc, const float* __restrict__ bfc,
    const float* __restrict__ wih, const float* __restrict__ bih,
    const float* __restrict__ bhh,
    const float* __restrict__ Wff, const float* __restrict__ bff,
    const float* __restrict__ ws, float* __restrict__ out) {

    __shared__ float hc[512];        // h = [0,256), c = [256,512)
    __shared__ float red1[1024];     // P1 partials [4 k-chunks][256 j]
    __shared__ float red2[1024];     // P2 partials [16 j-chunks][64 t]
    __shared__ float red3[1024];     // P3 partials [4 t-chunks][256 e]
    __shared__ float gbuf[1024];
    __shared__ float attnw[64];
    __shared__ float wa2s[256];
    __shared__ float wfcs[257];
    __shared__ float ys[64];
    __shared__ float ytil_s;
    __shared__ float epl[16384];     // EPT[b] : [256 j][64 t]
    __shared__ float encl[16384];    // enc[b] : [64 t][256 e]

    const int b    = blockIdx.x;
    const int tid  = threadIdx.x;
    const int lane = tid & 63;
    const int wv   = tid >> 6;

    // ---- stage per-batch data into LDS once ----
    const float* EPTb = ws + OFF_EPT + b * 16384;
    const float* encb = enc + b * 16384;
    #pragma unroll
    for (int i = 0; i < 16; ++i) {
        epl[i * 1024 + tid]  = EPTb[i * 1024 + tid];
        encl[i * 1024 + tid] = encb[i * 1024 + tid];
    }
    if (tid < 512) hc[tid] = 0.f;
    if (tid < 256) wa2s[tid] = Wa2[tid];
    if (tid < 257) wfcs[tid] = Wfc[tid];
    if (tid < NSTEP) ys[tid] = yhist[b * NSTEP + tid];
    const float bfc0 = bfc[0];
    const float wi   = wih[tid];                 // 4D x 1 -> per-thread gate row
    const float bsum = bih[tid] + bhh[tid];
    __syncthreads();

    const _Float16* PKH = (const _Float16*)(ws + OFF_PKH);
    const half8* PK1 = (const half8*)PKH;                  // [p][kk][j] half8
    const half8* PK4 = (const half8*)(PKH + 131072);       // [kk][q]    half8

    for (int step = 0; step < NSTEP; ++step) {
        // ---- P1 partials: red1[p][j] = sum_{k in chunk p} hc[k]*Wa1[j][k] ----
        {
            const int p = tid >> 8, j = tid & 255;
            const half8* W1 = PK1 + (p * 16) * 256 + j;
            const float* hp = hc + p * 128;
            float a0 = 0.f, a1 = 0.f;
            #pragma unroll 4
            for (int kk = 0; kk < 16; ++kk) {
                half8 w = W1[kk * 256];
                #pragma unroll
                for (int m = 0; m < 8; m += 2) {
                    a0 += hp[kk * 8 + m]     * (float)w[m];
                    a1 += hp[kk * 8 + m + 1] * (float)w[m + 1];
                }
            }
            red1[p * 256 + j] = a0 + a1;
        }
        // ---- P4 accumulate (registers): g[q] = h @ W_hh[q,:] ----
        float g0 = 0.f, g1 = 0.f;
        {
            const half8* W4 = PK4 + tid;                   // q = tid
            #pragma unroll 4
            for (int kk = 0; kk < 32; ++kk) {
                half8 w = W4[kk * 1024];
                #pragma unroll
                for (int m = 0; m < 8; m += 2) {
                    g0 += hc[kk * 8 + m]     * (float)w[m];
                    g1 += hc[kk * 8 + m + 1] * (float)w[m + 1];
                }
            }
        }
        __syncthreads();                                 // S1: red1 ready

        // ---- P2: scores s[t] = sum_j tanh(ep[j][t] + z[j]) * wa2[j] ----
        {
            float partial = 0.f;
            const int jbase = wv * 16;
            #pragma unroll
            for (int jj = 0; jj < 16; ++jj) {
                const int j = jbase + jj;
                float zj = red1[j] + red1[256 + j] + red1[512 + j] + red1[768 + j];
                float v = epl[j * 64 + lane] + zj;
                partial += ftanh(v) * wa2s[j];
            }
            red2[wv * 64 + lane] = partial;
        }
        __syncthreads();                                 // S2: red2 ready
        if (wv == 0) {
            float s = 0.f;
            #pragma unroll
            for (int w2 = 0; w2 < 16; ++w2) s += red2[w2 * 64 + lane];
            float m = s;
            #pragma unroll
            for (int d = 32; d >= 1; d >>= 1) m = fmaxf(m, __shfl_xor(m, d));
            float e = __expf(s - m);
            float su = e;
            #pragma unroll
            for (int d = 32; d >= 1; d >>= 1) su += __shfl_xor(su, d);
            attnw[lane] = e / su;
        }
        __syncthreads();                                 // S3: attnw ready

        // ---- P3: ctx partials ctx[e] = sum_t attn[t] * enc[t][e] ----
        {
            const int e = tid & 255, tc = tid >> 8;
            float partial = 0.f;
            #pragma unroll
            for (int i = 0; i < 16; ++i) {
                const int t = tc * 16 + i;
                partial += attnw[t] * encl[t * 256 + e];
            }
            red3[tc * 256 + e] = partial;
        }
        __syncthreads();                                 // S4: red3 ready
        if (wv == 0) {
            float partial = 0.f;
            #pragma unroll
            for (int q = 0; q < 4; ++q) {
                const int e2 = q * 64 + lane;
                float cv = red3[e2] + red3[256 + e2] + red3[512 + e2] + red3[768 + e2];
                partial += cv * wfcs[e2];
            }
            #pragma unroll
            for (int d = 32; d >= 1; d >>= 1) partial += __shfl_xor(partial, d);
            if (lane == 0) ytil_s = partial + wfcs[256] * ys[step] + bfc0;
        }
        __syncthreads();                                 // S5: ytil ready

        // ---- gates finalize + write ----
        gbuf[tid] = g0 + g1 + ytil_s * wi + bsum;
        __syncthreads();                                 // S6: gates ready

        // ---- h, c update (PyTorch gate order i,f,g,o) ----
        if (tid < 256) {
            float gi = gbuf[tid], gf = gbuf[256 + tid];
            float gg = gbuf[512 + tid], go = gbuf[768 + tid];
            float cn = fsig(gf) * hc[256 + tid] + fsig(gi) * ftanh(gg);
            float hn = fsig(go) * ftanh(cn);
            hc[tid] = hn; hc[256 + tid] = cn;
        }
        __syncthreads();                                 // S7: hc ready
    }

    // ---- epilogue: out[b][r] = b_ff[r] + [h, ctx] . W_ff[r]  (ctx from red3) ----
    if (wv < 2) {
        float partial = 0.f;
        #pragma unroll
        for (int qq = 0; qq < 8; ++qq) {
            const int e2 = qq * 64 + lane;
            float v;
            if (e2 < 256) {
                v = hc[e2];
            } else {
                const int e = e2 - 256;
                v = red3[e] + red3[256 + e] + red3[512 + e] + red3[768 + e];
            }
            partial += v * Wff[wv * 512 + e2];
        }
        #pragma unroll
        for (int d = 32; d >= 1; d >>= 1) partial += __shfl_xor(partial, d);
        if (lane == 0) out[b * 2 + wv] = partial + bff[wv];
    }
}

// ---------------------------------------------------------------------------
extern "C" void kernel_launch(void* const* d_in, const int* in_sizes, int n_in,
                              void* d_out, int out_size, void* d_ws, size_t ws_size,
                              hipStream_t stream) {
    const float* enc = (const float*)d_in[0];
    const float* yh  = (const float*)d_in[1];
    const float* Wa1 = (const float*)d_in[2];
    const float* ba1 = (const float*)d_in[3];
    const float* Wa2 = (const float*)d_in[4];
    // d_in[5] = b_a2 : softmax shift-invariant, unused
    const float* Wfc = (const float*)d_in[6];
    const float* bfc = (const float*)d_in[7];
    const float* Wih = (const float*)d_in[8];
    const float* Whh = (const float*)d_in[9];
    const float* bih = (const float*)d_in[10];
    const float* bhh = (const float*)d_in[11];
    const float* Wff = (const float*)d_in[12];
    const float* bff = (const float*)d_in[13];
    float* ws  = (float*)d_ws;
    float* out = (float*)d_out;

    hipLaunchKernelGGL(pack_weights, dim3(1792), dim3(256), 0, stream, Wa1, Whh, ws);
    hipLaunchKernelGGL(enc_proj_kernel, dim3(256), dim3(256), 0, stream, enc, ba1, ws);
    hipLaunchKernelGGL(decoder_main, dim3(BATCH), dim3(1024), 0, stream,
                       enc, yh, Wa2, Wfc, bfc, Wih, bih, bhh, Wff, bff, ws, out);
}

// Round 6
// 666.153 us; speedup vs baseline: 17.1934x; 1.0728x over previous
//
#include <hip/hip_runtime.h>
#include <math.h>

// Problem constants
#define BATCH 128
#define TENC  64
#define EE    256
#define DD    256
#define NSTEP 63

// Workspace layout (FLOAT offsets)
#define OFF_WA1ET  0         // [256 k][256 j] f32 : W_a1[j][512+k]   (enc part, for enc_proj)
#define OFF_EPT    65536     // [128 b][256 j][64 t] f32
#define OFF_PKH    2162688   // fp16 region (half offsets within):
                             //   PK1: [0,131072)      = [p<4][kk<16][j<256][m<8] = Wa1[j][p*128+kk*8+m]
                             //   PK4: [131072,393216) = [kk<32][q<1024][m<8]     = Whh[q][kk*8+m]
#define OFF_ZX     2359296   // [128 b][2 half][256] f32   z-half exchange
#define OFF_GX     2424832   // [128 b][2 half][1024] f32  gate-half exchange
#define OFF_FLAGS  2686976   // [128 b][2 half][2 which] uint, which: 0=z 1=g

typedef __attribute__((ext_vector_type(8))) _Float16 half8;

__device__ __forceinline__ float ftanh(float x) {
    x = fminf(15.f, fmaxf(-15.f, x));
    float e = __expf(2.f * x);
    return (e - 1.f) / (e + 1.f);
}
__device__ __forceinline__ float fsig(float x) {
    return 1.f / (1.f + __expf(-x));
}

// ---------------------------------------------------------------------------
// Pre-kernel A: pack weights (fp16 stream-ordered) + WA1ET (f32)
// ---------------------------------------------------------------------------
__global__ void pack_weights(const float* __restrict__ Wa1,
                             const float* __restrict__ Whh,
                             float* __restrict__ ws) {
    int idx = blockIdx.x * blockDim.x + threadIdx.x;
    _Float16* PKH = (_Float16*)(ws + OFF_PKH);
    if (idx < 131072) {
        int m = idx & 7, j = (idx >> 3) & 255, kk = (idx >> 11) & 15, p = idx >> 15;
        int k = p * 128 + kk * 8 + m;
        PKH[idx] = (_Float16)Wa1[j * 768 + k];
    } else if (idx < 393216) {
        int n = idx - 131072;
        int m = n & 7, q = (n >> 3) & 1023, kk = n >> 13;
        PKH[131072 + n] = (_Float16)Whh[q * 256 + kk * 8 + m];
    } else if (idx < 458752) {
        int n = idx - 393216;
        int k = n >> 8, j = n & 255;
        ws[OFF_WA1ET + n] = Wa1[j * 768 + 512 + k];
    }
}

// Pre-kernel A2: zero the exchange flags (every launch, before decoder)
__global__ void zero_flags(float* __restrict__ ws) {
    unsigned* f = (unsigned*)(ws + OFF_FLAGS);
    f[threadIdx.x] = 0u;
}

// ---------------------------------------------------------------------------
// Pre-kernel B: EPT[b][j][t] = b_a1[j] + sum_k enc[b][t][k] * W_a1[j][512+k]
// ---------------------------------------------------------------------------
__global__ void enc_proj_kernel(const float* __restrict__ enc,
                                const float* __restrict__ ba1,
                                float* __restrict__ ws) {
    __shared__ float smem[8448];
    const int b  = blockIdx.x >> 1;
    const int th = blockIdx.x & 1;
    const int t0 = th * 32;
    const int tid = threadIdx.x;

    const float* encb = enc + (b * TENC + t0) * 256;
    for (int c = 0; c < 32; ++c) smem[c * 256 + tid] = encb[c * 256 + tid];
    __syncthreads();

    const int w = tid >> 6, l = tid & 63;
    float acc[8][4];
    #pragma unroll
    for (int a = 0; a < 8; ++a)
        #pragma unroll
        for (int c = 0; c < 4; ++c) acc[a][c] = 0.f;

    const float4* WT = (const float4*)(ws + OFF_WA1ET);
    for (int k = 0; k < 256; ++k) {
        float4 wv = WT[k * 64 + l];
        #pragma unroll
        for (int tt = 0; tt < 8; ++tt) {
            float e = smem[(w * 8 + tt) * 256 + k];
            acc[tt][0] += e * wv.x; acc[tt][1] += e * wv.y;
            acc[tt][2] += e * wv.z; acc[tt][3] += e * wv.w;
        }
    }
    float4 bb = ((const float4*)ba1)[l];
    __syncthreads();
    #pragma unroll
    for (int tt = 0; tt < 8; ++tt) {
        smem[(4 * l + 0) * 33 + w * 8 + tt] = acc[tt][0] + bb.x;
        smem[(4 * l + 1) * 33 + w * 8 + tt] = acc[tt][1] + bb.y;
        smem[(4 * l + 2) * 33 + w * 8 + tt] = acc[tt][2] + bb.z;
        smem[(4 * l + 3) * 33 + w * 8 + tt] = acc[tt][3] + bb.w;
    }
    __syncthreads();
    float* EPT = ws + OFF_EPT + b * 16384;
    for (int c = 0; c < 32; ++c) {
        int i = c * 256 + tid;
        int j = i >> 5, t5 = i & 31;
        EPT[j * 64 + t0 + t5] = smem[j * 33 + t5];
    }
}

// ---------------------------------------------------------------------------
// Main kernel: 256 WGs = 2 per batch (pair (b, b+128)); each WG streams the
// k-half of both GEMVs (384 KB/step), attention computed redundantly,
// halves combined via LLC device atomics + step-numbered flags.
// Pair sums are 2-operand commutative -> both WGs hold bit-identical h,c.
// ---------------------------------------------------------------------------
__global__ __launch_bounds__(1024, 4) void decoder_main(
    const float* __restrict__ enc, const float* __restrict__ yhist,
    const float* __restrict__ Wa2,
    const float* __restrict__ Wfc, const float* __restrict__ bfc,
    const float* __restrict__ wih, const float* __restrict__ bih,
    const float* __restrict__ bhh,
    const float* __restrict__ Wff, const float* __restrict__ bff,
    float* __restrict__ ws, float* __restrict__ out) {

    __shared__ float hc[512];        // h = [0,256), c = [256,512)
    __shared__ float z[256];
    __shared__ float red1[1024];     // P1 partials [4 k-chunks of 64][256 j]
    __shared__ float red2[1024];     // P2 partials [16 j-chunks][64 t]
    __shared__ float red3[1024];     // P3 partials [4 t-chunks][256 e]
    __shared__ float gbuf[1024];
    __shared__ float attnw[64];
    __shared__ float wa2s[256];
    __shared__ float wfcs[257];
    __shared__ float ys[64];
    __shared__ float epl[16384];     // EPT[b] : [256 j][64 t]
    __shared__ float encl[16384];    // enc[b] : [64 t][256 e]

    const int bid  = blockIdx.x;
    const int b    = bid & 127;
    const int h    = bid >> 7;       // k-half owned by this WG
    const int tid  = threadIdx.x;
    const int lane = tid & 63;
    const int wv   = tid >> 6;

    // ---- stage per-batch data into LDS once ----
    const float* EPTb = ws + OFF_EPT + b * 16384;
    const float* encb = enc + b * 16384;
    #pragma unroll
    for (int i = 0; i < 16; ++i) {
        epl[i * 1024 + tid]  = EPTb[i * 1024 + tid];
        encl[i * 1024 + tid] = encb[i * 1024 + tid];
    }
    if (tid < 512) hc[tid] = 0.f;
    if (tid < 256) wa2s[tid] = Wa2[tid];
    if (tid < 257) wfcs[tid] = Wfc[tid];
    if (tid < NSTEP) ys[tid] = yhist[b * NSTEP + tid];
    const float bfc0 = bfc[0];
    const float wi   = wih[tid];
    const float bsum = bih[tid] + bhh[tid];
    __syncthreads();

    const _Float16* PKH = (const _Float16*)(ws + OFF_PKH);
    // P1: own 4 chunks of 64 k within half h
    const int c1 = tid >> 8, j1 = tid & 255;
    const int p1 = 2 * h + (c1 >> 1), kk01 = (c1 & 1) * 8;
    const half8* W1 = (const half8*)PKH + (p1 * 16 + kk01) * 256 + j1;
    const float* hp1 = hc + h * 256 + c1 * 64;
    // P4: own 16 kk (k-half of the 256-wide h vector), gate q = tid
    // W4 covers k = (16h+kk)*8 + m = h*128 + kk*8 + m  ->  state operand is
    // hc[h*128 + kk*8 + m]  (round-5 bug: used h*256, reading c instead of h)
    const half8* W4 = (const half8*)(PKH + 131072) + (16 * h) * 1024 + tid;
    const float* hg = hc + h * 128;

    // exchange buffers / flags
    float* ZXown = ws + OFF_ZX + (b * 2 + h) * 256;
    float* ZXpeer = ws + OFF_ZX + (b * 2 + (1 - h)) * 256;
    float* GXown = ws + OFF_GX + (b * 2 + h) * 1024;
    float* GXpeer = ws + OFF_GX + (b * 2 + (1 - h)) * 1024;
    unsigned* FLGown  = (unsigned*)(ws + OFF_FLAGS) + (b * 2 + h) * 2;
    unsigned* FLGpeer = (unsigned*)(ws + OFF_FLAGS) + (b * 2 + (1 - h)) * 2;

    for (int step = 0; step < NSTEP; ++step) {
        const unsigned tgt = (unsigned)(step + 1);
        // ---- P1 (own k-half): red1[c][j] = sum_{64 k} hc[k]*Wa1[j][k] ----
        {
            float a0 = 0.f, a1 = 0.f;
            #pragma unroll 4
            for (int it = 0; it < 8; ++it) {
                half8 w = W1[it * 256];
                #pragma unroll
                for (int m = 0; m < 8; m += 2) {
                    a0 += hp1[it * 8 + m]     * (float)w[m];
                    a1 += hp1[it * 8 + m + 1] * (float)w[m + 1];
                }
            }
            red1[c1 * 256 + j1] = a0 + a1;
        }
        __syncthreads();                                 // B1: red1 ready
        // ---- combine own z-half, post to peer ----
        if (tid < 256) {
            float zown = red1[tid] + red1[256 + tid] + red1[512 + tid] + red1[768 + tid];
            z[tid] = zown;
            atomicExch(&ZXown[tid], zown);
        }
        __syncthreads();                                 // B2: z atomics drained (vmcnt0)
        if (tid == 0) atomicExch(&FLGown[0], tgt);

        // ---- P4a: first 8 kk of own gate k-half (streams while peer works) ----
        float g0 = 0.f, g1 = 0.f;
        #pragma unroll 4
        for (int kk = 0; kk < 8; ++kk) {
            half8 w = W4[kk * 1024];
            #pragma unroll
            for (int m = 0; m < 8; m += 2) {
                g0 += hg[kk * 8 + m]     * (float)w[m];
                g1 += hg[kk * 8 + m + 1] * (float)w[m + 1];
            }
        }
        // ---- wait for peer z, combine ----
        if (tid == 0) {
            while (atomicAdd(&FLGpeer[0], 0u) < tgt) { __builtin_amdgcn_s_sleep(1); }
        }
        __syncthreads();                                 // B3: peer z posted
        if (tid < 256) {
            float zp = atomicAdd(&ZXpeer[tid], 0.f);
            z[tid] = z[tid] + zp;                        // commutative -> bit-identical in both WGs
        }
        __syncthreads();                                 // B4: z full

        // ---- P2: red2 partials + P4 chunk (kk 8..11) ----
        {
            float partial = 0.f;
            const int jbase = wv * 16;
            #pragma unroll
            for (int jj = 0; jj < 16; ++jj) {
                const int j = jbase + jj;
                float v = epl[j * 64 + lane] + z[j];
                partial += ftanh(v) * wa2s[j];
            }
            red2[wv * 64 + lane] = partial;
        }
        #pragma unroll
        for (int kk = 8; kk < 11; ++kk) {
            half8 w = W4[kk * 1024];
            #pragma unroll
            for (int m = 0; m < 8; m += 2) {
                g0 += hg[kk * 8 + m]     * (float)w[m];
                g1 += hg[kk * 8 + m + 1] * (float)w[m + 1];
            }
        }
        __syncthreads();                                 // B5: red2 ready
        // ---- softmax (wave 0) + P4 chunk (kk 11..14) ----
        if (wv == 0) {
            float s = 0.f;
            #pragma unroll
            for (int w2 = 0; w2 < 16; ++w2) s += red2[w2 * 64 + lane];
            float m = s;
            #pragma unroll
            for (int d = 32; d >= 1; d >>= 1) m = fmaxf(m, __shfl_xor(m, d));
            float e = __expf(s - m);
            float su = e;
            #pragma unroll
            for (int d = 32; d >= 1; d >>= 1) su += __shfl_xor(su, d);
            attnw[lane] = e / su;
        }
        #pragma unroll
        for (int kk = 11; kk < 14; ++kk) {
            half8 w = W4[kk * 1024];
            #pragma unroll
            for (int m = 0; m < 8; m += 2) {
                g0 += hg[kk * 8 + m]     * (float)w[m];
                g1 += hg[kk * 8 + m + 1] * (float)w[m + 1];
            }
        }
        __syncthreads();                                 // B6: attnw ready
        // ---- P3: ctx partials + P4 chunk (kk 14..16) ----
        {
            const int e = tid & 255, tc = tid >> 8;
            float partial = 0.f;
            #pragma unroll
            for (int i = 0; i < 16; ++i) {
                const int t = tc * 16 + i;
                partial += attnw[t] * encl[t * 256 + e];
            }
            red3[tc * 256 + e] = partial;
        }
        #pragma unroll
        for (int kk = 14; kk < 16; ++kk) {
            half8 w = W4[kk * 1024];
            #pragma unroll
            for (int m = 0; m < 8; m += 2) {
                g0 += hg[kk * 8 + m]     * (float)w[m];
                g1 += hg[kk * 8 + m + 1] * (float)w[m + 1];
            }
        }
        __syncthreads();                                 // B7: red3 ready

        // ---- ytil: per-wave redundant reduce (all waves get it in-register) ----
        float ytil;
        {
            float partial = 0.f;
            #pragma unroll
            for (int q = 0; q < 4; ++q) {
                const int e2 = q * 64 + lane;
                float cv = red3[e2] + red3[256 + e2] + red3[512 + e2] + red3[768 + e2];
                partial += cv * wfcs[e2];
            }
            #pragma unroll
            for (int d = 32; d >= 1; d >>= 1) partial += __shfl_xor(partial, d);
            ytil = partial + wfcs[256] * ys[step] + bfc0;
        }
        // ---- post own gate-half ----
        const float gown = g0 + g1;
        atomicExch(&GXown[tid], gown);
        __syncthreads();                                 // B8: g atomics drained
        if (tid == 0) {
            atomicExch(&FLGown[1], tgt);
            while (atomicAdd(&FLGpeer[1], 0u) < tgt) { __builtin_amdgcn_s_sleep(1); }
        }
        __syncthreads();                                 // B9: peer g posted
        {
            float gp = atomicAdd(&GXpeer[tid], 0.f);
            gbuf[tid] = gown + gp + ytil * wi + bsum;    // commutative pair sum
        }
        __syncthreads();                                 // B10: gates ready
        // ---- h, c update (redundant in both WGs, bit-identical) ----
        if (tid < 256) {
            float gi = gbuf[tid], gf = gbuf[256 + tid];
            float gg = gbuf[512 + tid], go = gbuf[768 + tid];
            float cn = fsig(gf) * hc[256 + tid] + fsig(gi) * ftanh(gg);
            float hn = fsig(go) * ftanh(cn);
            hc[tid] = hn; hc[256 + tid] = cn;
        }
        __syncthreads();                                 // B11: hc ready
    }

    // ---- epilogue: only half 0 writes out ----
    if (h == 0 && wv < 2) {
        float partial = 0.f;
        #pragma unroll
        for (int qq = 0; qq < 8; ++qq) {
            const int e2 = qq * 64 + lane;
            float v;
            if (e2 < 256) {
                v = hc[e2];
            } else {
                const int e = e2 - 256;
                v = red3[e] + red3[256 + e] + red3[512 + e] + red3[768 + e];
            }
            partial += v * Wff[wv * 512 + e2];
        }
        #pragma unroll
        for (int d = 32; d >= 1; d >>= 1) partial += __shfl_xor(partial, d);
        if (lane == 0) out[b * 2 + wv] = partial + bff[wv];
    }
}

// ---------------------------------------------------------------------------
extern "C" void kernel_launch(void* const* d_in, const int* in_sizes, int n_in,
                              void* d_out, int out_size, void* d_ws, size_t ws_size,
                              hipStream_t stream) {
    const float* enc = (const float*)d_in[0];
    const float* yh  = (const float*)d_in[1];
    const float* Wa1 = (const float*)d_in[2];
    const float* ba1 = (const float*)d_in[3];
    const float* Wa2 = (const float*)d_in[4];
    // d_in[5] = b_a2 : softmax shift-invariant, unused
    const float* Wfc = (const float*)d_in[6];
    const float* bfc = (const float*)d_in[7];
    const float* Wih = (const float*)d_in[8];
    const float* Whh = (const float*)d_in[9];
    const float* bih = (const float*)d_in[10];
    const float* bhh = (const float*)d_in[11];
    const float* Wff = (const float*)d_in[12];
    const float* bff = (const float*)d_in[13];
    float* ws  = (float*)d_ws;
    float* out = (float*)d_out;

    hipLaunchKernelGGL(pack_weights, dim3(1792), dim3(256), 0, stream, Wa1, Whh, ws);
    hipLaunchKernelGGL(zero_flags, dim3(1), dim3(512), 0, stream, ws);
    hipLaunchKernelGGL(enc_proj_kernel, dim3(256), dim3(256), 0, stream, enc, ba1, ws);
    hipLaunchKernelGGL(decoder_main, dim3(256), dim3(1024), 0, stream,
                       enc, yh, Wa2, Wfc, bfc, Wih, bih, bhh, Wff, bff, ws, out);
}